// Round 13
// baseline (3027.401 us; speedup 1.0000x reference)
//
#include <hip/hip_runtime.h>

#define B_ 4
#define S_ 4096
#define D_ 512
#define H_ 8
#define L_ 6
#define M_ 2048
#define DH_ 64
#define NC_ 64   // number of chunks = S/C
#define C_ 64    // chunk length

typedef _Float16 half8 __attribute__((ext_vector_type(8)));
typedef _Float16 half4 __attribute__((ext_vector_type(4)));
typedef float f32x4 __attribute__((ext_vector_type(4)));

typedef const __attribute__((address_space(1))) unsigned int gu32;
typedef __attribute__((address_space(3))) unsigned int lu32;

// ---------------------------------------------------------------------------
// Embedding + sinusoidal positional encoding (f64 PE recipe — r3 fix)
// ---------------------------------------------------------------------------
__global__ __launch_bounds__(128) void embed_kernel(const int* __restrict__ tokens,
                                                    const float* __restrict__ emb,
                                                    float* __restrict__ x) {
  int row = blockIdx.x;            // b*S + s
  int s = row & (S_ - 1);
  int tok = tokens[row];
  const float4* e = (const float4*)(emb + (size_t)tok * D_);
  float4* xo = (float4*)(x + (size_t)row * D_);
  int t = threadIdx.x;             // 128 threads, 4 floats each
  float4 ev = e[t];
  int d0 = t * 4;
  const double c64 = -9.210340371976184 / 255.0;   // -ln(10000)/(half-1)
  float pe[4];
#pragma unroll
  for (int j = 0; j < 4; j++) {
    int d = d0 + j;
    int i = (d < 256) ? d : d - 256;
    double freq = exp((double)i * c64);
    double arg = (double)s * freq;
    pe[j] = (d < 256) ? (float)sin(arg) : (float)cos(arg);
  }
  float4 o;
  o.x = ev.x + pe[0];
  o.y = ev.y + pe[1];
  o.z = ev.z + pe[2];
  o.w = ev.w + pe[3];
  xo[t] = o;
}

// ---------------------------------------------------------------------------
// LayerNorm variants. ln_h writes fp16 hi/lo planes; ln_f writes f32.
// ---------------------------------------------------------------------------
__device__ __forceinline__ void ln_core(const float* __restrict__ in, int row, int t,
                                        const float* __restrict__ sc,
                                        const float* __restrict__ bi,
                                        float4& o1, float4& o2) {
  const float4* ir = (const float4*)(in + (size_t)row * D_);
  float4 a = ir[t];
  float4 b4 = ir[t + 64];
  float sum = a.x + a.y + a.z + a.w + b4.x + b4.y + b4.z + b4.w;
  float sq  = a.x*a.x + a.y*a.y + a.z*a.z + a.w*a.w
            + b4.x*b4.x + b4.y*b4.y + b4.z*b4.z + b4.w*b4.w;
#pragma unroll
  for (int m = 1; m < 64; m <<= 1) {
    sum += __shfl_xor(sum, m);
    sq  += __shfl_xor(sq, m);
  }
  float mean = sum * (1.0f / 512.0f);
  float var  = sq * (1.0f / 512.0f) - mean * mean;
  float rstd = 1.0f / sqrtf(var + 1e-6f);
  float4 s1 = ((const float4*)sc)[t], s2 = ((const float4*)sc)[t + 64];
  float4 g1 = ((const float4*)bi)[t], g2 = ((const float4*)bi)[t + 64];
  o1.x = (a.x - mean) * rstd * s1.x + g1.x;
  o1.y = (a.y - mean) * rstd * s1.y + g1.y;
  o1.z = (a.z - mean) * rstd * s1.z + g1.z;
  o1.w = (a.w - mean) * rstd * s1.w + g1.w;
  o2.x = (b4.x - mean) * rstd * s2.x + g2.x;
  o2.y = (b4.y - mean) * rstd * s2.y + g2.y;
  o2.z = (b4.z - mean) * rstd * s2.z + g2.z;
  o2.w = (b4.w - mean) * rstd * s2.w + g2.w;
}

__global__ __launch_bounds__(64) void ln_h(const float* __restrict__ in,
                                           _Float16* __restrict__ hi,
                                           _Float16* __restrict__ lo,
                                           const float* __restrict__ sc,
                                           const float* __restrict__ bi) {
  int row = blockIdx.x, t = threadIdx.x;
  float4 o1, o2;
  ln_core(in, row, t, sc, bi, o1, o2);
  float v1[4] = {o1.x, o1.y, o1.z, o1.w};
  float v2[4] = {o2.x, o2.y, o2.z, o2.w};
  half4 h1, l1, h2, l2;
#pragma unroll
  for (int j = 0; j < 4; j++) {
    _Float16 h = (_Float16)v1[j];
    h1[j] = h; l1[j] = (_Float16)(v1[j] - (float)h);
    _Float16 g = (_Float16)v2[j];
    h2[j] = g; l2[j] = (_Float16)(v2[j] - (float)g);
  }
  size_t base = (size_t)row * D_;
  *(half4*)&hi[base + t * 4] = h1;
  *(half4*)&hi[base + 256 + t * 4] = h2;
  *(half4*)&lo[base + t * 4] = l1;
  *(half4*)&lo[base + 256 + t * 4] = l2;
}

__global__ __launch_bounds__(64) void ln_f(const float* __restrict__ in,
                                           float* __restrict__ out,
                                           const float* __restrict__ sc,
                                           const float* __restrict__ bi) {
  int row = blockIdx.x, t = threadIdx.x;
  float4 o1, o2;
  ln_core(in, row, t, sc, bi, o1, o2);
  float4* orow = (float4*)(out + (size_t)row * D_);
  orow[t] = o1;
  orow[t + 64] = o2;
}

__device__ __forceinline__ float gelu_f(float v) {
  float v3 = v * v * v;
  return 0.5f * v * (1.0f + tanhf(0.7978845608028654f * (v + 0.044715f * v3)));
}

// ---------------------------------------------------------------------------
// Weight convert+transpose: src f32 [K][N] -> dst hi/lo fp16 [N][K].
// ---------------------------------------------------------------------------
__global__ __launch_bounds__(256) void transp_cvt(const float* __restrict__ src,
                                                  _Float16* __restrict__ dhi,
                                                  _Float16* __restrict__ dlo,
                                                  int K, int N) {
  __shared__ float tile[32][33];
  int n0 = blockIdx.x * 32, k0 = blockIdx.y * 32;
  int tx = threadIdx.x & 31, ty = threadIdx.x >> 5;   // ty 0..7
#pragma unroll
  for (int i = 0; i < 4; i++)
    tile[ty + 8 * i][tx] = src[(size_t)(k0 + ty + 8 * i) * N + n0 + tx];
  __syncthreads();
#pragma unroll
  for (int i = 0; i < 4; i++) {
    int n = n0 + ty + 8 * i;
    float v = tile[tx][ty + 8 * i];
    _Float16 h = (_Float16)v;
    dhi[(size_t)n * K + k0 + tx] = h;
    dlo[(size_t)n * K + k0 + tx] = (_Float16)(v - (float)h);
  }
}

// ---------------------------------------------------------------------------
// fp16x3 split MFMA GEMM — counted-vmcnt deep pipeline (T3/T4/T5).
// 128(M)x256(N) tile, 8 waves (512 thr), BK=32, 3 LDS buffers (144 KB).
// Per K-step: vmcnt(6) [keep next-step loads in flight] -> s_barrier ->
// issue stage(t+2) -> ds_read frags -> setprio(1) MFMAx48 setprio(0).
// Stage(t) provably landed in ALL waves before buf[t%3] is read (per-wave
// FIFO vmcnt + barrier); buffer overwritten at t is the one read at t-1,
// and stages issue only post-barrier -> no race.
// OPERAND-SWAPPED MFMA (r12): bit-identical accumulation (same k-order,
// same product order per acc element).
// A: [M][lda] planes, B: [N][ldb] planes (pre-transposed weights).
// ---------------------------------------------------------------------------
template <int HAS_BIAS, int RESID, int DO_GELU, int OUT_HALF>
__global__ __launch_bounds__(512) void gemm_h(const _Float16* __restrict__ Ahi,
                                              const _Float16* __restrict__ Alo,
                                              const _Float16* __restrict__ Bhi,
                                              const _Float16* __restrict__ Blo,
                                              const float* __restrict__ bias,
                                              float* __restrict__ C,
                                              _Float16* __restrict__ Chi,
                                              _Float16* __restrict__ Clo,
                                              int M, int N, int K, int lda, int ldb) {
  // per buffer (halfs): Ahi[128*32]@0, Alo@4096, Bhi[256*32]@8192, Blo@16384
  __shared__ _Float16 lds[3][24576];   // 144 KB
  int tid = threadIdx.x;
  // XCD-aware bijective swizzle (nwg % 8 == 0 guaranteed by host).
  int nwg = gridDim.x * gridDim.y;
  int flat = blockIdx.y * gridDim.x + blockIdx.x;
  int chunk = nwg >> 3;
  int nf = (flat & 7) * chunk + (flat >> 3);
  int bx = nf % gridDim.x, by = nf / gridDim.x;
  int row0 = by * 128, col0 = bx * 256;
  int lane = tid & 63, w = tid >> 6;        // 8 waves
  int wm = w >> 2, wn = w & 3;              // wave -> 64x64 output quadrant
  int fr = lane & 15, fk = (lane >> 4) * 8;
  int q4 = (lane >> 4) * 4;

  // Staging: 48 x 1KB chunks per K-step; wave w owns chunks w*6..w*6+5.
  // Chunk c: c<16 -> A planes (8 chunks each); else B planes (16 each).
  // LDS dest is wave-uniform base (lane offset = lane*16B implicit);
  // global src is per-lane: row = prow + (lane>>2), col halfs = (lane&3)*8.
  const _Float16* srcs[6];
  unsigned ldsof[6];
#pragma unroll
  for (int i = 0; i < 6; i++) {
    int c = w * 6 + i;
    const _Float16* pb;
    int ld, base, prow;
    unsigned poff;
    if (c < 16) {
      int pl = c >> 3; prow = (c & 7) * 16;
      pb = pl ? Alo : Ahi; ld = lda; base = row0; poff = pl ? 4096u : 0u;
    } else {
      int c2 = c - 16; int pl = c2 >> 4; prow = (c2 & 15) * 16;
      pb = pl ? Blo : Bhi; ld = ldb; base = col0; poff = pl ? 16384u : 8192u;
    }
    srcs[i] = pb + (size_t)(base + prow + (lane >> 2)) * ld + (lane & 3) * 8;
    ldsof[i] = poff + (unsigned)prow * 32u;
  }

  f32x4 acc[4][4];
#pragma unroll
  for (int m = 0; m < 4; m++)
#pragma unroll
    for (int n = 0; n < 4; n++) acc[m][n] = (f32x4){0.f, 0.f, 0.f, 0.f};

  int nst = K >> 5;
  // prologue: stage steps 0 and 1
#pragma unroll
  for (int i = 0; i < 6; i++)
    __builtin_amdgcn_global_load_lds((gu32*)srcs[i], (lu32*)&lds[0][ldsof[i]], 16, 0, 0);
#pragma unroll
  for (int i = 0; i < 6; i++)
    __builtin_amdgcn_global_load_lds((gu32*)(srcs[i] + 32), (lu32*)&lds[1][ldsof[i]], 16, 0, 0);

  int ir = 0;
  for (int t = 0; t < nst; ++t) {
    if (t + 1 < nst) {
      asm volatile("s_waitcnt vmcnt(6)" ::: "memory");   // stage(t) landed; stage(t+1) in flight
    } else {
      asm volatile("s_waitcnt vmcnt(0)" ::: "memory");
    }
    __builtin_amdgcn_s_barrier();                         // all waves' stage(t) landed
    if (t + 2 < nst) {
      int ib = ir + 2; if (ib >= 3) ib -= 3;
      int off = (t + 2) * 32;
#pragma unroll
      for (int i = 0; i < 6; i++)
        __builtin_amdgcn_global_load_lds((gu32*)(srcs[i] + off), (lu32*)&lds[ib][ldsof[i]], 16, 0, 0);
    }
    const _Float16* Ah_ = &lds[ir][0];
    const _Float16* Al_ = &lds[ir][4096];
    const _Float16* Bh_ = &lds[ir][8192];
    const _Float16* Bl_ = &lds[ir][16384];
    half8 bhf[4], blf[4];
#pragma unroll
    for (int n = 0; n < 4; n++) {
      int col = wn * 64 + n * 16 + fr;
      bhf[n] = *(const half8*)&Bh_[col * 32 + fk];
      blf[n] = *(const half8*)&Bl_[col * 32 + fk];
    }
    __builtin_amdgcn_s_setprio(1);
#pragma unroll
    for (int m = 0; m < 4; m++) {
      int row = wm * 64 + m * 16 + fr;
      half8 ah = *(const half8*)&Ah_[row * 32 + fk];
      half8 al = *(const half8*)&Al_[row * 32 + fk];
#pragma unroll
      for (int n = 0; n < 4; n++)
        acc[m][n] = __builtin_amdgcn_mfma_f32_16x16x32_f16(bhf[n], ah, acc[m][n], 0, 0, 0);
#pragma unroll
      for (int n = 0; n < 4; n++)
        acc[m][n] = __builtin_amdgcn_mfma_f32_16x16x32_f16(bhf[n], al, acc[m][n], 0, 0, 0);
#pragma unroll
      for (int n = 0; n < 4; n++)
        acc[m][n] = __builtin_amdgcn_mfma_f32_16x16x32_f16(blf[n], ah, acc[m][n], 0, 0, 0);
    }
    __builtin_amdgcn_s_setprio(0);
    ir = ir + 1; if (ir >= 3) ir -= 3;
  }

  // ---- epilogue: lane holds C[row][colb..colb+3] per (m,n) ----
#pragma unroll
  for (int m = 0; m < 4; m++) {
    int row = row0 + wm * 64 + m * 16 + fr;
#pragma unroll
    for (int n = 0; n < 4; n++) {
      int colb = col0 + wn * 64 + n * 16 + q4;
      float4 bq = {0.f, 0.f, 0.f, 0.f};
      if (HAS_BIAS) bq = *(const float4*)&bias[colb];
      float v[4];
      v[0] = acc[m][n][0] + bq.x;
      v[1] = acc[m][n][1] + bq.y;
      v[2] = acc[m][n][2] + bq.z;
      v[3] = acc[m][n][3] + bq.w;
      if (DO_GELU) {
        v[0] = gelu_f(v[0]); v[1] = gelu_f(v[1]);
        v[2] = gelu_f(v[2]); v[3] = gelu_f(v[3]);
      }
      size_t idx = (size_t)row * N + colb;
      if (OUT_HALF) {
        half4 hv, lv;
#pragma unroll
        for (int r = 0; r < 4; r++) {
          _Float16 h = (_Float16)v[r];
          hv[r] = h;
          lv[r] = (_Float16)(v[r] - (float)h);
        }
        *(half4*)&Chi[idx] = hv;
        *(half4*)&Clo[idx] = lv;
      } else {
        float4 vv;
        vv.x = v[0]; vv.y = v[1]; vv.z = v[2]; vv.w = v[3];
        if (RESID) {
          float4 old = *(const float4*)&C[idx];
          vv.x += old.x; vv.y += old.y; vv.z += old.z; vv.w += old.w;
        }
        *(float4*)&C[idx] = vv;
      }
    }
  }
}

// ---------------------------------------------------------------------------
// rotW2[d][h*32+j] = sum_f Wq[d][h*64+f] * rot[h][f][j]  (f64 acc, f32 store)
// ---------------------------------------------------------------------------
__global__ __launch_bounds__(256) void rotw_kernel(const float* __restrict__ Wq,
                                                   const float* __restrict__ rot,
                                                   float* __restrict__ rotW2) {
  int idx = blockIdx.x * 256 + threadIdx.x;   // d*256 + h*32 + j, 512*256 total
  int n = idx & 255;
  int d = idx >> 8;
  int h = n >> 5;
  int j = n & 31;
  double a = 0.0;
#pragma unroll 8
  for (int f = 0; f < 64; f++) {
    a += (double)Wq[(size_t)d * D_ + h * 64 + f] * (double)rot[((size_t)h * 64 + f) * 32 + j];
  }
  rotW2[idx] = (float)a;
}

// ---------------------------------------------------------------------------
// Per-token bucket argmax over [r, -r] (first-index ties, like np.argmax).
// Reads hash scores from the fused qvr planes (cols 1024..1279, pitch 1280).
// ---------------------------------------------------------------------------
__global__ __launch_bounds__(256) void argmax_kernel(const _Float16* __restrict__ qvr_hi,
                                                     const _Float16* __restrict__ qvr_lo,
                                                     int* __restrict__ buckets) {
  int gid = blockIdx.x * 256 + threadIdx.x;   // b*H*S + h*S + s
  int s = gid & (S_ - 1);
  int bh = gid >> 12;
  int h = bh & (H_ - 1);
  int b = bh >> 3;
  size_t base = ((size_t)b * S_ + s) * 1280 + 1024 + h * 32;
  float r[32];
#pragma unroll
  for (int j8 = 0; j8 < 4; j8++) {
    half8 hv = *(const half8*)&qvr_hi[base + j8 * 8];
    half8 lv = *(const half8*)&qvr_lo[base + j8 * 8];
#pragma unroll
    for (int e = 0; e < 8; e++)
      r[j8 * 8 + e] = (float)hv[e] + (float)lv[e];
  }
  float best = r[0];
  int bi = 0;
#pragma unroll
  for (int j = 1; j < 64; j++) {
    float val = (j < 32) ? r[j] : -r[j - 32];
    if (val > best) { best = val; bi = j; }
  }
  buckets[gid] = bi;
}

// ---------------------------------------------------------------------------
// Stable counting sort by bucket (== argsort(bucket*S + pos)).
// ---------------------------------------------------------------------------
__global__ __launch_bounds__(64) void sort_kernel(const int* __restrict__ buckets,
                                                  int* __restrict__ st) {
  __shared__ int hist[64][64];   // [thread][bucket]
  __shared__ int boff[64];
  int bh = blockIdx.x;
  const int* bk = buckets + (size_t)bh * S_;
  int* stb = st + (size_t)bh * S_;
  int t = threadIdx.x;
  for (int j = 0; j < 64; j++) hist[t][j] = 0;
  __syncthreads();
  for (int i = 0; i < 64; i++) {
    int s = t * 64 + i;
    hist[t][bk[s]]++;
  }
  __syncthreads();
  int run = 0;
  for (int tt = 0; tt < 64; tt++) {
    int c = hist[tt][t];
    hist[tt][t] = run;
    run += c;
  }
  boff[t] = run;
  __syncthreads();
  if (t == 0) {
    int acc = 0;
    for (int j = 0; j < 64; j++) { int c = boff[j]; boff[j] = acc; acc += c; }
  }
  __syncthreads();
  for (int i = 0; i < 64; i++) {
    int s = t * 64 + i;
    int bkt = bk[s];
    int pos = boff[bkt] + hist[t][bkt];
    hist[t][bkt] = hist[t][bkt] + 1;
    stb[pos] = s;
  }
}

// ---------------------------------------------------------------------------
// MFMA chunked shared-QK attention (fp16x3). Reads fused qvr planes
// (pitch 1280). PV uses operand-swapped MFMA -> half4 epilogue stores.
// ---------------------------------------------------------------------------
#define KP 72
#define VP 136
__global__ __launch_bounds__(256) void attn_mfma(const _Float16* __restrict__ qvhi,
                                                 const _Float16* __restrict__ qvlo,
                                                 const int* __restrict__ st,
                                                 _Float16* __restrict__ ohi,
                                                 _Float16* __restrict__ olo) {
  __shared__ _Float16 lds[35840];   // 71680 B
  const int KH = 0, KL = 9216, VH = 18432, VL = 27136;
  int blk = blockIdx.x;
  int n = blk & (NC_ - 1);
  int bh = blk >> 6;
  int h = bh & (H_ - 1);
  int b = bh >> 3;
  const int* stbh = st + (size_t)bh * S_;
  int tid = threadIdx.x;
  int pn = (n + NC_ - 1) & (NC_ - 1);

  // ---- stage K (=Q) rows and V^T into LDS ----
  {
    int r = tid >> 1, dseg = (tid & 1) * 32;
    int si = (r < 64) ? (n * 64 + r) : (pn * 64 + (r - 64));
    int p = stbh[si];
    size_t gb = ((size_t)b * S_ + p) * 1280 + h * 64 + dseg;
    half8 kh[4], kl[4], vh8[4], vl8[4];
#pragma unroll
    for (int j = 0; j < 4; j++) {
      kh[j] = *(const half8*)&qvhi[gb + j * 8];
      kl[j] = *(const half8*)&qvlo[gb + j * 8];
      vh8[j] = *(const half8*)&qvhi[gb + 512 + j * 8];
      vl8[j] = *(const half8*)&qvlo[gb + 512 + j * 8];
    }
#pragma unroll
    for (int j = 0; j < 4; j++) {
      *(half8*)&lds[KH + r * KP + dseg + j * 8] = kh[j];
      *(half8*)&lds[KL + r * KP + dseg + j * 8] = kl[j];
    }
#pragma unroll
    for (int j = 0; j < 4; j++) {
#pragma unroll
      for (int e = 0; e < 8; e++) {
        int dim = dseg + j * 8 + e;
        lds[VH + dim * VP + r] = vh8[j][e];
        lds[VL + dim * VP + r] = vl8[j][e];
      }
    }
  }
  __syncthreads();

  int lane = tid & 63, w = tid >> 6;
  int fr = lane & 15, fk8 = (lane >> 4) * 8;
  int q4 = (lane >> 4) * 4;

  // ---- QK^T: wave w computes S[w*16..+16][0..128] ----
  int qrow = w * 16 + fr;
  half8 qh0 = *(half8*)&lds[KH + qrow * KP + fk8];
  half8 qh1 = *(half8*)&lds[KH + qrow * KP + 32 + fk8];
  half8 ql0 = *(half8*)&lds[KL + qrow * KP + fk8];
  half8 ql1 = *(half8*)&lds[KL + qrow * KP + 32 + fk8];

  f32x4 sa[8];
#pragma unroll
  for (int nc = 0; nc < 8; nc++) {
    int key = nc * 16 + fr;
    half8 bh0 = *(half8*)&lds[KH + key * KP + fk8];
    half8 bh1 = *(half8*)&lds[KH + key * KP + 32 + fk8];
    half8 bl0 = *(half8*)&lds[KL + key * KP + fk8];
    half8 bl1 = *(half8*)&lds[KL + key * KP + 32 + fk8];
    f32x4 a = (f32x4){0.f, 0.f, 0.f, 0.f};
    a = __builtin_amdgcn_mfma_f32_16x16x32_f16(qh0, bh0, a, 0, 0, 0);
    a = __builtin_amdgcn_mfma_f32_16x16x32_f16(qh1, bh1, a, 0, 0, 0);
    a = __builtin_amdgcn_mfma_f32_16x16x32_f16(ql0, bh0, a, 0, 0, 0);
    a = __builtin_amdgcn_mfma_f32_16x16x32_f16(ql1, bh1, a, 0, 0, 0);
    a = __builtin_amdgcn_mfma_f32_16x16x32_f16(qh0, bl0, a, 0, 0, 0);
    a = __builtin_amdgcn_mfma_f32_16x16x32_f16(qh1, bl1, a, 0, 0, 0);
    sa[nc] = a;
  }

  // ---- softmax over 128 keys per query row (row = (lane>>4)*4+reg) ----
  float inv[4];
#pragma unroll
  for (int reg = 0; reg < 4; reg++) {
    float m = sa[0][reg];
#pragma unroll
    for (int nc = 1; nc < 8; nc++) m = fmaxf(m, sa[nc][reg]);
    m = fmaxf(m, __shfl_xor(m, 1));
    m = fmaxf(m, __shfl_xor(m, 2));
    m = fmaxf(m, __shfl_xor(m, 4));
    m = fmaxf(m, __shfl_xor(m, 8));
    float s = 0.f;
#pragma unroll
    for (int nc = 0; nc < 8; nc++) {
      float e = expf(0.125f * (sa[nc][reg] - m));
      sa[nc][reg] = e;
      s += e;
    }
    s += __shfl_xor(s, 1);
    s += __shfl_xor(s, 2);
    s += __shfl_xor(s, 4);
    s += __shfl_xor(s, 8);
    inv[reg] = 1.0f / s;
  }

  __syncthreads();   // all waves done reading K region; safe to alias with P

  // ---- write P (= e/sum) hi/lo into per-wave LDS region ----
  int PW = w * 4352;
#pragma unroll
  for (int nc = 0; nc < 8; nc++) {
#pragma unroll
    for (int reg = 0; reg < 4; reg++) {
      float pv = sa[nc][reg] * inv[reg];
      _Float16 ph = (_Float16)pv;
      _Float16 pl = (_Float16)(pv - (float)ph);
      int prow = (lane >> 4) * 4 + reg;
      int key = nc * 16 + fr;
      lds[PW + prow * VP + key] = ph;
      lds[PW + 2176 + prow * VP + key] = pl;
    }
  }

  // ---- PV: O[16][64] per wave (operand-swapped: reg-dim = 4 consec dims) ----
  half8 ph8[4], pl8[4];
#pragma unroll
  for (int kt = 0; kt < 4; kt++) {
    ph8[kt] = *(half8*)&lds[PW + fr * VP + kt * 32 + fk8];
    pl8[kt] = *(half8*)&lds[PW + 2176 + fr * VP + kt * 32 + fk8];
  }
  f32x4 oa[4];
#pragma unroll
  for (int nco = 0; nco < 4; nco++) {
    int dim = nco * 16 + fr;
    f32x4 a = (f32x4){0.f, 0.f, 0.f, 0.f};
#pragma unroll
    for (int kt = 0; kt < 4; kt++) {
      half8 bvh = *(half8*)&lds[VH + dim * VP + kt * 32 + fk8];
      half8 bvl = *(half8*)&lds[VL + dim * VP + kt * 32 + fk8];
      a = __builtin_amdgcn_mfma_f32_16x16x32_f16(bvh, ph8[kt], a, 0, 0, 0);
      a = __builtin_amdgcn_mfma_f32_16x16x32_f16(bvh, pl8[kt], a, 0, 0, 0);
      a = __builtin_amdgcn_mfma_f32_16x16x32_f16(bvl, ph8[kt], a, 0, 0, 0);
    }
    oa[nco] = a;
  }

  // ---- epilogue: lane owns query fr, dims nco*16+q4..+3 -> half4 stores ----
  {
    int qq = w * 16 + fr;
    int p = stbh[n * 64 + qq];
    size_t ob = ((size_t)b * S_ + p) * D_ + h * 64;
#pragma unroll
    for (int nco = 0; nco < 4; nco++) {
      half4 hv, lv;
#pragma unroll
      for (int r = 0; r < 4; r++) {
        float val = oa[nco][r];
        _Float16 h16 = (_Float16)val;
        hv[r] = h16;
        lv[r] = (_Float16)(val - (float)h16);
      }
      *(half4*)&ohi[ob + nco * 16 + q4] = hv;
      *(half4*)&olo[ob + nco * 16 + q4] = lv;
    }
  }
}

// ---------------------------------------------------------------------------
extern "C" void kernel_launch(void* const* d_in, const int* in_sizes, int n_in,
                              void* d_out, int out_size, void* d_ws, size_t ws_size,
                              hipStream_t stream) {
  const int*   tokens = (const int*)d_in[0];
  const float* emb    = (const float*)d_in[1];
  const float* rot    = (const float*)d_in[2];
  const float* ln1_s  = (const float*)d_in[3];
  const float* ln1_b  = (const float*)d_in[4];
  const float* Wq     = (const float*)d_in[5];
  const float* Wv     = (const float*)d_in[6];
  const float* Wo     = (const float*)d_in[7];
  const float* ln2_s  = (const float*)d_in[8];
  const float* ln2_b  = (const float*)d_in[9];
  const float* W1     = (const float*)d_in[10];
  const float* b1     = (const float*)d_in[11];
  const float* W2     = (const float*)d_in[12];
  const float* b2     = (const float*)d_in[13];
  const float* lnf_s  = (const float*)d_in[14];
  const float* lnf_b  = (const float*)d_in[15];

  float* x = (float*)d_out;                  // residual stream lives in d_out
  const size_t RS = (size_t)B_ * S_ * D_;    // 8388608 elements
  // weight planes: WqT|WvT|rotW2T|WoT|W1T|W2T  (transposed [n][k])
  const size_t WTOT = 3 * (size_t)D_ * D_ + 2 * (size_t)D_ * M_ + 256 * 512;

  char* wsb = (char*)d_ws;
  const int rows = B_ * S_;                  // 16384
  // region: 14RS bytes, phase-aliased.
  _Float16* qvr_hi = (_Float16*)wsb;
  _Float16* qvr_lo = qvr_hi + (size_t)rows * 1280;
  _Float16* obuf_hi = (_Float16*)(wsb + 2 * (size_t)rows * 1280 * 2);
  _Float16* obuf_lo = obuf_hi + RS;
  _Float16* mid_hi = (_Float16*)wsb;                  // [rows][1024] (FFN phase)
  _Float16* mid_lo = (_Float16*)(wsb + 4 * RS);
  _Float16* hbuf_hi = (_Float16*)(wsb + 14 * RS);
  _Float16* hbuf_lo = (_Float16*)(wsb + 16 * RS);
  _Float16* whi = (_Float16*)(wsb + 18 * RS);
  _Float16* wlo = whi + WTOT;
  float* rotW2 = (float*)(wlo + WTOT);                // [512*256] f32
  int* buckets = (int*)(rotW2 + 512 * 256);
  int* stbuf   = buckets + B_ * H_ * S_;
  // total: 18RS (151.0MB) + 12.06MB + 1.6MB ~= 164.7MB

  const size_t OQ = 0;                                // WqT [512][512]
  const size_t OV = (size_t)D_ * D_;                  // WvT [512][512]
  const size_t OR = 2 * (size_t)D_ * D_;              // rotW2T [256][512]
  const size_t OO = OR + (size_t)256 * 512;           // WoT [512][512]
  const size_t O1 = OO + (size_t)D_ * D_;             // W1T [2048][512]
  const size_t O2 = O1 + (size_t)D_ * M_;             // W2T [512][2048]

  const int Mh = M_ / 2;                     // 1024

  embed_kernel<<<rows, 128, 0, stream>>>(tokens, emb, x);

  for (int l = 0; l < L_; l++) {
    transp_cvt<<<dim3(D_ / 32, D_ / 32), 256, 0, stream>>>(Wq + (size_t)l * D_ * D_, whi + OQ, wlo + OQ, D_, D_);
    transp_cvt<<<dim3(D_ / 32, D_ / 32), 256, 0, stream>>>(Wv + (size_t)l * D_ * D_, whi + OV, wlo + OV, D_, D_);
    transp_cvt<<<dim3(D_ / 32, D_ / 32), 256, 0, stream>>>(Wo + (size_t)l * D_ * D_, whi + OO, wlo + OO, D_, D_);
    transp_cvt<<<dim3(M_ / 32, D_ / 32), 256, 0, stream>>>(W1 + (size_t)l * D_ * M_, whi + O1, wlo + O1, D_, M_);
    transp_cvt<<<dim3(D_ / 32, M_ / 32), 256, 0, stream>>>(W2 + (size_t)l * M_ * D_, whi + O2, wlo + O2, M_, D_);
    rotw_kernel<<<(D_ * 256) / 256, 256, 0, stream>>>(Wq + (size_t)l * D_ * D_,
                                                      rot + (size_t)l * H_ * DH_ * 32, rotW2);
    transp_cvt<<<dim3(256 / 32, D_ / 32), 256, 0, stream>>>(rotW2, whi + OR, wlo + OR, D_, 256);

    ln_h<<<rows, 64, 0, stream>>>(x, hbuf_hi, hbuf_lo, ln1_s + (size_t)l * D_, ln1_b + (size_t)l * D_);

    // fused Q+V+hash projection: B = [WqT ; WvT ; rotW2T] (1280 rows, pitch 512)
    dim3 gqv(1280 / 256, rows / 128);
    gemm_h<0, 0, 0, 1><<<gqv, 512, 0, stream>>>(hbuf_hi, hbuf_lo, whi + OQ, wlo + OQ, nullptr,
                                                nullptr, qvr_hi, qvr_lo, rows, 1280, D_, D_, D_);

    argmax_kernel<<<(B_ * H_ * S_) / 256, 256, 0, stream>>>(qvr_hi, qvr_lo, buckets);
    sort_kernel<<<B_ * H_, 64, 0, stream>>>(buckets, stbuf);
    attn_mfma<<<B_ * H_ * NC_, 256, 0, stream>>>(qvr_hi, qvr_lo, stbuf, obuf_hi, obuf_lo);

    dim3 g1(D_ / 256, rows / 128);
    gemm_h<0, 1, 0, 0><<<g1, 512, 0, stream>>>(obuf_hi, obuf_lo, whi + OO, wlo + OO, nullptr,
                                               x, nullptr, nullptr, rows, D_, D_, D_, D_);

    ln_h<<<rows, 64, 0, stream>>>(x, hbuf_hi, hbuf_lo, ln2_s + (size_t)l * D_, ln2_b + (size_t)l * D_);

    // FFN in two 1024-column halves (mid planes sized [rows][1024])
    for (int ch = 0; ch < 2; ch++) {
      dim3 gf1(Mh / 256, rows / 128);
      gemm_h<1, 0, 1, 1><<<gf1, 512, 0, stream>>>(hbuf_hi, hbuf_lo,
                                                  whi + O1 + (size_t)ch * Mh * D_,
                                                  wlo + O1 + (size_t)ch * Mh * D_,
                                                  b1 + (size_t)l * M_ + ch * Mh,
                                                  nullptr, mid_hi, mid_lo, rows, Mh, D_, D_, D_);
      dim3 gf2(D_ / 256, rows / 128);
      if (ch == 0) {
        gemm_h<0, 1, 0, 0><<<gf2, 512, 0, stream>>>(mid_hi, mid_lo,
                                                    whi + O2,
                                                    wlo + O2,
                                                    nullptr, x, nullptr, nullptr,
                                                    rows, D_, Mh, Mh, M_);
      } else {
        gemm_h<1, 1, 0, 0><<<gf2, 512, 0, stream>>>(mid_hi, mid_lo,
                                                    whi + O2 + (size_t)ch * Mh,
                                                    wlo + O2 + (size_t)ch * Mh,
                                                    b2 + (size_t)l * D_, x, nullptr, nullptr,
                                                    rows, D_, Mh, Mh, M_);
      }
    }
  }

  ln_f<<<rows, 64, 0, stream>>>(x, x, lnf_s, lnf_b);
}

// Round 14
// 2846.252 us; speedup vs baseline: 1.0636x; 1.0636x over previous
//
#include <hip/hip_runtime.h>

#define B_ 4
#define S_ 4096
#define D_ 512
#define H_ 8
#define L_ 6
#define M_ 2048
#define DH_ 64
#define NC_ 64   // number of chunks = S/C
#define C_ 64    // chunk length

typedef _Float16 half8 __attribute__((ext_vector_type(8)));
typedef _Float16 half4 __attribute__((ext_vector_type(4)));
typedef float f32x4 __attribute__((ext_vector_type(4)));

typedef const __attribute__((address_space(1))) unsigned int gu32;
typedef __attribute__((address_space(3))) unsigned int lu32;

// weight-plane offsets (halfs): WqT|WvT|rotW2T|WoT|W1T|W2T, all [n][k]
#define OQ_ 0
#define OV_ 262144
#define OR_ 524288
#define OO_ 655360
#define O1_ 917504
#define O2_ 1966080
#define WTOT_ 3014656

// ---------------------------------------------------------------------------
// Embedding + sinusoidal positional encoding (f64 PE recipe — r3 fix)
// ---------------------------------------------------------------------------
__global__ __launch_bounds__(128) void embed_kernel(const int* __restrict__ tokens,
                                                    const float* __restrict__ emb,
                                                    float* __restrict__ x) {
  int row = blockIdx.x;            // b*S + s
  int s = row & (S_ - 1);
  int tok = tokens[row];
  const float4* e = (const float4*)(emb + (size_t)tok * D_);
  float4* xo = (float4*)(x + (size_t)row * D_);
  int t = threadIdx.x;             // 128 threads, 4 floats each
  float4 ev = e[t];
  int d0 = t * 4;
  const double c64 = -9.210340371976184 / 255.0;   // -ln(10000)/(half-1)
  float pe[4];
#pragma unroll
  for (int j = 0; j < 4; j++) {
    int d = d0 + j;
    int i = (d < 256) ? d : d - 256;
    double freq = exp((double)i * c64);
    double arg = (double)s * freq;
    pe[j] = (d < 256) ? (float)sin(arg) : (float)cos(arg);
  }
  float4 o;
  o.x = ev.x + pe[0];
  o.y = ev.y + pe[1];
  o.z = ev.z + pe[2];
  o.w = ev.w + pe[3];
  xo[t] = o;
}

// ---------------------------------------------------------------------------
// LayerNorm variants (4 rows per 256-thr block; one wave per row).
// ln_h writes fp16 hi/lo planes; ln_f writes f32.
// ---------------------------------------------------------------------------
__device__ __forceinline__ void ln_core(const float* __restrict__ in, int row, int t,
                                        const float* __restrict__ sc,
                                        const float* __restrict__ bi,
                                        float4& o1, float4& o2) {
  const float4* ir = (const float4*)(in + (size_t)row * D_);
  float4 a = ir[t];
  float4 b4 = ir[t + 64];
  float sum = a.x + a.y + a.z + a.w + b4.x + b4.y + b4.z + b4.w;
  float sq  = a.x*a.x + a.y*a.y + a.z*a.z + a.w*a.w
            + b4.x*b4.x + b4.y*b4.y + b4.z*b4.z + b4.w*b4.w;
#pragma unroll
  for (int m = 1; m < 64; m <<= 1) {
    sum += __shfl_xor(sum, m);
    sq  += __shfl_xor(sq, m);
  }
  float mean = sum * (1.0f / 512.0f);
  float var  = sq * (1.0f / 512.0f) - mean * mean;
  float rstd = 1.0f / sqrtf(var + 1e-6f);
  float4 s1 = ((const float4*)sc)[t], s2 = ((const float4*)sc)[t + 64];
  float4 g1 = ((const float4*)bi)[t], g2 = ((const float4*)bi)[t + 64];
  o1.x = (a.x - mean) * rstd * s1.x + g1.x;
  o1.y = (a.y - mean) * rstd * s1.y + g1.y;
  o1.z = (a.z - mean) * rstd * s1.z + g1.z;
  o1.w = (a.w - mean) * rstd * s1.w + g1.w;
  o2.x = (b4.x - mean) * rstd * s2.x + g2.x;
  o2.y = (b4.y - mean) * rstd * s2.y + g2.y;
  o2.z = (b4.z - mean) * rstd * s2.z + g2.z;
  o2.w = (b4.w - mean) * rstd * s2.w + g2.w;
}

__global__ __launch_bounds__(256) void ln_h(const float* __restrict__ in,
                                            _Float16* __restrict__ hi,
                                            _Float16* __restrict__ lo,
                                            const float* __restrict__ sc,
                                            const float* __restrict__ bi) {
  int row = blockIdx.x * 4 + (threadIdx.x >> 6);
  int t = threadIdx.x & 63;
  float4 o1, o2;
  ln_core(in, row, t, sc, bi, o1, o2);
  float v1[4] = {o1.x, o1.y, o1.z, o1.w};
  float v2[4] = {o2.x, o2.y, o2.z, o2.w};
  half4 h1, l1, h2, l2;
#pragma unroll
  for (int j = 0; j < 4; j++) {
    _Float16 h = (_Float16)v1[j];
    h1[j] = h; l1[j] = (_Float16)(v1[j] - (float)h);
    _Float16 g = (_Float16)v2[j];
    h2[j] = g; l2[j] = (_Float16)(v2[j] - (float)g);
  }
  size_t base = (size_t)row * D_;
  *(half4*)&hi[base + t * 4] = h1;
  *(half4*)&hi[base + 256 + t * 4] = h2;
  *(half4*)&lo[base + t * 4] = l1;
  *(half4*)&lo[base + 256 + t * 4] = l2;
}

__global__ __launch_bounds__(256) void ln_f(const float* __restrict__ in,
                                            float* __restrict__ out,
                                            const float* __restrict__ sc,
                                            const float* __restrict__ bi) {
  int row = blockIdx.x * 4 + (threadIdx.x >> 6);
  int t = threadIdx.x & 63;
  float4 o1, o2;
  ln_core(in, row, t, sc, bi, o1, o2);
  float4* orow = (float4*)(out + (size_t)row * D_);
  orow[t] = o1;
  orow[t + 64] = o2;
}

__device__ __forceinline__ float gelu_f(float v) {
  float v3 = v * v * v;
  return 0.5f * v * (1.0f + tanhf(0.7978845608028654f * (v + 0.044715f * v3)));
}

// ---------------------------------------------------------------------------
// Weight convert+transpose: src f32 [K][N] -> dst hi/lo fp16 [N][K].
// Generic single-matrix version (used for rotW2 after rotw_kernel).
// ---------------------------------------------------------------------------
__device__ __forceinline__ void transp_tile(const float* __restrict__ src,
                                            _Float16* __restrict__ dhi,
                                            _Float16* __restrict__ dlo,
                                            int K, int N, int n0, int k0,
                                            float (*tile)[33]) {
  int tx = threadIdx.x & 31, ty = threadIdx.x >> 5;   // ty 0..7
#pragma unroll
  for (int i = 0; i < 4; i++)
    tile[ty + 8 * i][tx] = src[(size_t)(k0 + ty + 8 * i) * N + n0 + tx];
  __syncthreads();
#pragma unroll
  for (int i = 0; i < 4; i++) {
    int n = n0 + ty + 8 * i;
    float v = tile[tx][ty + 8 * i];
    _Float16 h = (_Float16)v;
    dhi[(size_t)n * K + k0 + tx] = h;
    dlo[(size_t)n * K + k0 + tx] = (_Float16)(v - (float)h);
  }
}

__global__ __launch_bounds__(256) void transp_cvt(const float* __restrict__ src,
                                                  _Float16* __restrict__ dhi,
                                                  _Float16* __restrict__ dlo,
                                                  int K, int N) {
  __shared__ float tile[32][33];
  transp_tile(src, dhi, dlo, K, N, blockIdx.x * 32, blockIdx.y * 32, tile);
}

// One launch for all 5 per-layer weight transposes (range-switched).
__global__ __launch_bounds__(256) void transp_all(const float* __restrict__ Wq,
                                                  const float* __restrict__ Wv,
                                                  const float* __restrict__ Wo,
                                                  const float* __restrict__ W1,
                                                  const float* __restrict__ W2,
                                                  _Float16* __restrict__ whi,
                                                  _Float16* __restrict__ wlo) {
  __shared__ float tile[32][33];
  int bid = blockIdx.x;
  const float* src; _Float16 *dhi, *dlo; int K, N, t;
  if (bid < 256)       { src = Wq; dhi = whi + OQ_; dlo = wlo + OQ_; K = 512; N = 512;  t = bid; }
  else if (bid < 512)  { src = Wv; dhi = whi + OV_; dlo = wlo + OV_; K = 512; N = 512;  t = bid - 256; }
  else if (bid < 768)  { src = Wo; dhi = whi + OO_; dlo = wlo + OO_; K = 512; N = 512;  t = bid - 512; }
  else if (bid < 1792) { src = W1; dhi = whi + O1_; dlo = wlo + O1_; K = 512; N = 2048; t = bid - 768; }
  else                 { src = W2; dhi = whi + O2_; dlo = wlo + O2_; K = 2048; N = 512; t = bid - 1792; }
  int nx = N / 32;
  int n0 = (t % nx) * 32, k0 = (t / nx) * 32;
  transp_tile(src, dhi, dlo, K, N, n0, k0, tile);
}

// ---------------------------------------------------------------------------
// fp16x3 split MFMA GEMM, global_load_lds double-buffered + XCD swizzle
// (r12-proven structure). OPERAND-SWAPPED MFMA -> half4/float4 epilogue.
// A: [M][lda] planes, B: [N][ldb] planes. 128x128 tile, BK=32, 4 waves.
// ---------------------------------------------------------------------------
template <int HAS_BIAS, int RESID, int DO_GELU, int OUT_HALF>
__global__ __launch_bounds__(256) void gemm_h(const _Float16* __restrict__ Ahi,
                                              const _Float16* __restrict__ Alo,
                                              const _Float16* __restrict__ Bhi,
                                              const _Float16* __restrict__ Blo,
                                              const float* __restrict__ bias,
                                              float* __restrict__ C,
                                              _Float16* __restrict__ Chi,
                                              _Float16* __restrict__ Clo,
                                              int M, int N, int K, int lda, int ldb) {
  __shared__ _Float16 lds[2][4][128 * 32];   // 64 KB
  int tid = threadIdx.x;
  // XCD-aware bijective swizzle (nwg % 8 == 0 guaranteed by host).
  int nwg = gridDim.x * gridDim.y;
  int flat = blockIdx.y * gridDim.x + blockIdx.x;
  int chunk = nwg >> 3;
  int nf = (flat & 7) * chunk + (flat >> 3);
  int bx = nf % gridDim.x, by = nf / gridDim.x;
  int row0 = by * 128, col0 = bx * 128;
  int lane = tid & 63, w = tid >> 6;
  int wm = w >> 1, wn = w & 1;
  int fr = lane & 15, fk = (lane >> 4) * 8;
  int q4 = (lane >> 4) * 4;

  // per-lane global source: wave w stages plane w
  int sld = (w < 2) ? lda : ldb;
  int sbase = (w < 2) ? row0 : col0;
  const _Float16* plane = (w == 0) ? Ahi : (w == 1) ? Alo : (w == 2) ? Bhi : Blo;
  const _Float16* gsrc = plane + (size_t)(sbase + (lane >> 2)) * sld + (lane & 3) * 8;
  size_t rowstep = (size_t)16 * sld;   // 16 rows per 1KB chunk

  f32x4 acc[4][4];
#pragma unroll
  for (int m = 0; m < 4; m++)
#pragma unroll
    for (int n = 0; n < 4; n++) acc[m][n] = (f32x4){0.f, 0.f, 0.f, 0.f};

  int nst = K >> 5;
#pragma unroll
  for (int i = 0; i < 8; i++) {
    __builtin_amdgcn_global_load_lds((gu32*)(gsrc + (size_t)i * rowstep),
                                     (lu32*)&lds[0][w][i * 512], 16, 0, 0);
  }
  __syncthreads();

  int cur = 0;
  for (int s = 0; s < nst; ++s) {
    if (s + 1 < nst) {
      const _Float16* g = gsrc + (size_t)(s + 1) * 32;
#pragma unroll
      for (int i = 0; i < 8; i++) {
        __builtin_amdgcn_global_load_lds((gu32*)(g + (size_t)i * rowstep),
                                         (lu32*)&lds[cur ^ 1][w][i * 512], 16, 0, 0);
      }
    }
    const _Float16* Ah_ = lds[cur][0];
    const _Float16* Al_ = lds[cur][1];
    const _Float16* Bh_ = lds[cur][2];
    const _Float16* Bl_ = lds[cur][3];
    half8 bhf[4], blf[4];
#pragma unroll
    for (int n = 0; n < 4; n++) {
      int col = wn * 64 + n * 16 + fr;
      bhf[n] = *(const half8*)&Bh_[col * 32 + fk];
      blf[n] = *(const half8*)&Bl_[col * 32 + fk];
    }
#pragma unroll
    for (int m = 0; m < 4; m++) {
      int row = wm * 64 + m * 16 + fr;
      half8 ah = *(const half8*)&Ah_[row * 32 + fk];
      half8 al = *(const half8*)&Al_[row * 32 + fk];
      // operand-swapped: same products, same order
#pragma unroll
      for (int n = 0; n < 4; n++)
        acc[m][n] = __builtin_amdgcn_mfma_f32_16x16x32_f16(bhf[n], ah, acc[m][n], 0, 0, 0);
#pragma unroll
      for (int n = 0; n < 4; n++)
        acc[m][n] = __builtin_amdgcn_mfma_f32_16x16x32_f16(bhf[n], al, acc[m][n], 0, 0, 0);
#pragma unroll
      for (int n = 0; n < 4; n++)
        acc[m][n] = __builtin_amdgcn_mfma_f32_16x16x32_f16(blf[n], ah, acc[m][n], 0, 0, 0);
    }
    __syncthreads();
    cur ^= 1;
  }

  // ---- epilogue: lane holds C[row][colb..colb+3] per (m,n) ----
#pragma unroll
  for (int m = 0; m < 4; m++) {
    int row = row0 + wm * 64 + m * 16 + fr;
#pragma unroll
    for (int n = 0; n < 4; n++) {
      int colb = col0 + wn * 64 + n * 16 + q4;
      float4 bq = {0.f, 0.f, 0.f, 0.f};
      if (HAS_BIAS) bq = *(const float4*)&bias[colb];
      float v[4];
      v[0] = acc[m][n][0] + bq.x;
      v[1] = acc[m][n][1] + bq.y;
      v[2] = acc[m][n][2] + bq.z;
      v[3] = acc[m][n][3] + bq.w;
      if (DO_GELU) {
        v[0] = gelu_f(v[0]); v[1] = gelu_f(v[1]);
        v[2] = gelu_f(v[2]); v[3] = gelu_f(v[3]);
      }
      size_t idx = (size_t)row * N + colb;
      if (OUT_HALF) {
        half4 hv, lv;
#pragma unroll
        for (int r = 0; r < 4; r++) {
          _Float16 h = (_Float16)v[r];
          hv[r] = h;
          lv[r] = (_Float16)(v[r] - (float)h);
        }
        *(half4*)&Chi[idx] = hv;
        *(half4*)&Clo[idx] = lv;
      } else {
        float4 vv;
        vv.x = v[0]; vv.y = v[1]; vv.z = v[2]; vv.w = v[3];
        if (RESID) {
          float4 old = *(const float4*)&C[idx];
          vv.x += old.x; vv.y += old.y; vv.z += old.z; vv.w += old.w;
        }
        *(float4*)&C[idx] = vv;
      }
    }
  }
}

// ---------------------------------------------------------------------------
// rotW2[d][h*32+j] = sum_f Wq[d][h*64+f] * rot[h][f][j]  (f64 acc, f32 store)
// ---------------------------------------------------------------------------
__global__ __launch_bounds__(256) void rotw_kernel(const float* __restrict__ Wq,
                                                   const float* __restrict__ rot,
                                                   float* __restrict__ rotW2) {
  int idx = blockIdx.x * 256 + threadIdx.x;   // d*256 + h*32 + j, 512*256 total
  int n = idx & 255;
  int d = idx >> 8;
  int h = n >> 5;
  int j = n & 31;
  double a = 0.0;
#pragma unroll 8
  for (int f = 0; f < 64; f++) {
    a += (double)Wq[(size_t)d * D_ + h * 64 + f] * (double)rot[((size_t)h * 64 + f) * 32 + j];
  }
  rotW2[idx] = (float)a;
}

// ---------------------------------------------------------------------------
// Per-token bucket argmax over [r, -r] (first-index ties, like np.argmax).
// Reads hash scores from the fused qvr planes (cols 1024..1279, pitch 1280).
// ---------------------------------------------------------------------------
__global__ __launch_bounds__(256) void argmax_kernel(const _Float16* __restrict__ qvr_hi,
                                                     const _Float16* __restrict__ qvr_lo,
                                                     int* __restrict__ buckets) {
  int gid = blockIdx.x * 256 + threadIdx.x;   // b*H*S + h*S + s
  int s = gid & (S_ - 1);
  int bh = gid >> 12;
  int h = bh & (H_ - 1);
  int b = bh >> 3;
  size_t base = ((size_t)b * S_ + s) * 1280 + 1024 + h * 32;
  float r[32];
#pragma unroll
  for (int j8 = 0; j8 < 4; j8++) {
    half8 hv = *(const half8*)&qvr_hi[base + j8 * 8];
    half8 lv = *(const half8*)&qvr_lo[base + j8 * 8];
#pragma unroll
    for (int e = 0; e < 8; e++)
      r[j8 * 8 + e] = (float)hv[e] + (float)lv[e];
  }
  float best = r[0];
  int bi = 0;
#pragma unroll
  for (int j = 1; j < 64; j++) {
    float val = (j < 32) ? r[j] : -r[j - 32];
    if (val > best) { best = val; bi = j; }
  }
  buckets[gid] = bi;
}

// ---------------------------------------------------------------------------
// Stable counting sort by bucket (== argsort(bucket*S + pos)).
// ---------------------------------------------------------------------------
__global__ __launch_bounds__(64) void sort_kernel(const int* __restrict__ buckets,
                                                  int* __restrict__ st) {
  __shared__ int hist[64][64];   // [thread][bucket]
  __shared__ int boff[64];
  int bh = blockIdx.x;
  const int* bk = buckets + (size_t)bh * S_;
  int* stb = st + (size_t)bh * S_;
  int t = threadIdx.x;
  for (int j = 0; j < 64; j++) hist[t][j] = 0;
  __syncthreads();
  for (int i = 0; i < 64; i++) {
    int s = t * 64 + i;
    hist[t][bk[s]]++;
  }
  __syncthreads();
  int run = 0;
  for (int tt = 0; tt < 64; tt++) {
    int c = hist[tt][t];
    hist[tt][t] = run;
    run += c;
  }
  boff[t] = run;
  __syncthreads();
  if (t == 0) {
    int acc = 0;
    for (int j = 0; j < 64; j++) { int c = boff[j]; boff[j] = acc; acc += c; }
  }
  __syncthreads();
  for (int i = 0; i < 64; i++) {
    int s = t * 64 + i;
    int bkt = bk[s];
    int pos = boff[bkt] + hist[t][bkt];
    hist[t][bkt] = hist[t][bkt] + 1;
    stb[pos] = s;
  }
}

// ---------------------------------------------------------------------------
// MFMA chunked shared-QK attention (fp16x3). Reads fused qvr planes
// (pitch 1280). PV uses operand-swapped MFMA -> half4 epilogue stores.
// ---------------------------------------------------------------------------
#define KP 72
#define VP 136
__global__ __launch_bounds__(256) void attn_mfma(const _Float16* __restrict__ qvhi,
                                                 const _Float16* __restrict__ qvlo,
                                                 const int* __restrict__ st,
                                                 _Float16* __restrict__ ohi,
                                                 _Float16* __restrict__ olo) {
  __shared__ _Float16 lds[35840];   // 71680 B
  const int KH = 0, KL = 9216, VH = 18432, VL = 27136;
  int blk = blockIdx.x;
  int n = blk & (NC_ - 1);
  int bh = blk >> 6;
  int h = bh & (H_ - 1);
  int b = bh >> 3;
  const int* stbh = st + (size_t)bh * S_;
  int tid = threadIdx.x;
  int pn = (n + NC_ - 1) & (NC_ - 1);

  // ---- stage K (=Q) rows and V^T into LDS ----
  {
    int r = tid >> 1, dseg = (tid & 1) * 32;
    int si = (r < 64) ? (n * 64 + r) : (pn * 64 + (r - 64));
    int p = stbh[si];
    size_t gb = ((size_t)b * S_ + p) * 1280 + h * 64 + dseg;
    half8 kh[4], kl[4], vh8[4], vl8[4];
#pragma unroll
    for (int j = 0; j < 4; j++) {
      kh[j] = *(const half8*)&qvhi[gb + j * 8];
      kl[j] = *(const half8*)&qvlo[gb + j * 8];
      vh8[j] = *(const half8*)&qvhi[gb + 512 + j * 8];
      vl8[j] = *(const half8*)&qvlo[gb + 512 + j * 8];
    }
#pragma unroll
    for (int j = 0; j < 4; j++) {
      *(half8*)&lds[KH + r * KP + dseg + j * 8] = kh[j];
      *(half8*)&lds[KL + r * KP + dseg + j * 8] = kl[j];
    }
#pragma unroll
    for (int j = 0; j < 4; j++) {
#pragma unroll
      for (int e = 0; e < 8; e++) {
        int dim = dseg + j * 8 + e;
        lds[VH + dim * VP + r] = vh8[j][e];
        lds[VL + dim * VP + r] = vl8[j][e];
      }
    }
  }
  __syncthreads();

  int lane = tid & 63, w = tid >> 6;
  int fr = lane & 15, fk8 = (lane >> 4) * 8;
  int q4 = (lane >> 4) * 4;

  // ---- QK^T: wave w computes S[w*16..+16][0..128] ----
  int qrow = w * 16 + fr;
  half8 qh0 = *(half8*)&lds[KH + qrow * KP + fk8];
  half8 qh1 = *(half8*)&lds[KH + qrow * KP + 32 + fk8];
  half8 ql0 = *(half8*)&lds[KL + qrow * KP + fk8];
  half8 ql1 = *(half8*)&lds[KL + qrow * KP + 32 + fk8];

  f32x4 sa[8];
#pragma unroll
  for (int nc = 0; nc < 8; nc++) {
    int key = nc * 16 + fr;
    half8 bh0 = *(half8*)&lds[KH + key * KP + fk8];
    half8 bh1 = *(half8*)&lds[KH + key * KP + 32 + fk8];
    half8 bl0 = *(half8*)&lds[KL + key * KP + fk8];
    half8 bl1 = *(half8*)&lds[KL + key * KP + 32 + fk8];
    f32x4 a = (f32x4){0.f, 0.f, 0.f, 0.f};
    a = __builtin_amdgcn_mfma_f32_16x16x32_f16(qh0, bh0, a, 0, 0, 0);
    a = __builtin_amdgcn_mfma_f32_16x16x32_f16(qh1, bh1, a, 0, 0, 0);
    a = __builtin_amdgcn_mfma_f32_16x16x32_f16(ql0, bh0, a, 0, 0, 0);
    a = __builtin_amdgcn_mfma_f32_16x16x32_f16(ql1, bh1, a, 0, 0, 0);
    a = __builtin_amdgcn_mfma_f32_16x16x32_f16(qh0, bl0, a, 0, 0, 0);
    a = __builtin_amdgcn_mfma_f32_16x16x32_f16(qh1, bl1, a, 0, 0, 0);
    sa[nc] = a;
  }

  // ---- softmax over 128 keys per query row (row = (lane>>4)*4+reg) ----
  float inv[4];
#pragma unroll
  for (int reg = 0; reg < 4; reg++) {
    float m = sa[0][reg];
#pragma unroll
    for (int nc = 1; nc < 8; nc++) m = fmaxf(m, sa[nc][reg]);
    m = fmaxf(m, __shfl_xor(m, 1));
    m = fmaxf(m, __shfl_xor(m, 2));
    m = fmaxf(m, __shfl_xor(m, 4));
    m = fmaxf(m, __shfl_xor(m, 8));
    float s = 0.f;
#pragma unroll
    for (int nc = 0; nc < 8; nc++) {
      float e = expf(0.125f * (sa[nc][reg] - m));
      sa[nc][reg] = e;
      s += e;
    }
    s += __shfl_xor(s, 1);
    s += __shfl_xor(s, 2);
    s += __shfl_xor(s, 4);
    s += __shfl_xor(s, 8);
    inv[reg] = 1.0f / s;
  }

  __syncthreads();   // all waves done reading K region; safe to alias with P

  // ---- write P (= e/sum) hi/lo into per-wave LDS region ----
  int PW = w * 4352;
#pragma unroll
  for (int nc = 0; nc < 8; nc++) {
#pragma unroll
    for (int reg = 0; reg < 4; reg++) {
      float pv = sa[nc][reg] * inv[reg];
      _Float16 ph = (_Float16)pv;
      _Float16 pl = (_Float16)(pv - (float)ph);
      int prow = (lane >> 4) * 4 + reg;
      int key = nc * 16 + fr;
      lds[PW + prow * VP + key] = ph;
      lds[PW + 2176 + prow * VP + key] = pl;
    }
  }

  // ---- PV: O[16][64] per wave (operand-swapped: reg-dim = 4 consec dims) ----
  half8 ph8[4], pl8[4];
#pragma unroll
  for (int kt = 0; kt < 4; kt++) {
    ph8[kt] = *(half8*)&lds[PW + fr * VP + kt * 32 + fk8];
    pl8[kt] = *(half8*)&lds[PW + 2176 + fr * VP + kt * 32 + fk8];
  }
  f32x4 oa[4];
#pragma unroll
  for (int nco = 0; nco < 4; nco++) {
    int dim = nco * 16 + fr;
    f32x4 a = (f32x4){0.f, 0.f, 0.f, 0.f};
#pragma unroll
    for (int kt = 0; kt < 4; kt++) {
      half8 bvh = *(half8*)&lds[VH + dim * VP + kt * 32 + fk8];
      half8 bvl = *(half8*)&lds[VL + dim * VP + kt * 32 + fk8];
      a = __builtin_amdgcn_mfma_f32_16x16x32_f16(bvh, ph8[kt], a, 0, 0, 0);
      a = __builtin_amdgcn_mfma_f32_16x16x32_f16(bvh, pl8[kt], a, 0, 0, 0);
      a = __builtin_amdgcn_mfma_f32_16x16x32_f16(bvl, ph8[kt], a, 0, 0, 0);
    }
    oa[nco] = a;
  }

  // ---- epilogue: lane owns query fr, dims nco*16+q4..+3 -> half4 stores ----
  {
    int qq = w * 16 + fr;
    int p = stbh[n * 64 + qq];
    size_t ob = ((size_t)b * S_ + p) * D_ + h * 64;
#pragma unroll
    for (int nco = 0; nco < 4; nco++) {
      half4 hv, lv;
#pragma unroll
      for (int r = 0; r < 4; r++) {
        float val = oa[nco][r];
        _Float16 h16 = (_Float16)val;
        hv[r] = h16;
        lv[r] = (_Float16)(val - (float)h16);
      }
      *(half4*)&ohi[ob + nco * 16 + q4] = hv;
      *(half4*)&olo[ob + nco * 16 + q4] = lv;
    }
  }
}

// ---------------------------------------------------------------------------
extern "C" void kernel_launch(void* const* d_in, const int* in_sizes, int n_in,
                              void* d_out, int out_size, void* d_ws, size_t ws_size,
                              hipStream_t stream) {
  const int*   tokens = (const int*)d_in[0];
  const float* emb    = (const float*)d_in[1];
  const float* rot    = (const float*)d_in[2];
  const float* ln1_s  = (const float*)d_in[3];
  const float* ln1_b  = (const float*)d_in[4];
  const float* Wq     = (const float*)d_in[5];
  const float* Wv     = (const float*)d_in[6];
  const float* Wo     = (const float*)d_in[7];
  const float* ln2_s  = (const float*)d_in[8];
  const float* ln2_b  = (const float*)d_in[9];
  const float* W1     = (const float*)d_in[10];
  const float* b1     = (const float*)d_in[11];
  const float* W2     = (const float*)d_in[12];
  const float* b2     = (const float*)d_in[13];
  const float* lnf_s  = (const float*)d_in[14];
  const float* lnf_b  = (const float*)d_in[15];

  float* x = (float*)d_out;                  // residual stream lives in d_out
  const size_t RS = (size_t)B_ * S_ * D_;    // 8388608 elements
  const size_t WTOT = WTOT_;

  char* wsb = (char*)d_ws;
  const int rows = B_ * S_;                  // 16384
  // region: 14RS bytes, phase-aliased.
  _Float16* qvr_hi = (_Float16*)wsb;
  _Float16* qvr_lo = qvr_hi + (size_t)rows * 1280;
  _Float16* obuf_hi = (_Float16*)(wsb + 2 * (size_t)rows * 1280 * 2);
  _Float16* obuf_lo = obuf_hi + RS;
  _Float16* mid_hi = (_Float16*)wsb;                  // [rows][1024] (FFN phase)
  _Float16* mid_lo = (_Float16*)(wsb + 4 * RS);
  _Float16* hbuf_hi = (_Float16*)(wsb + 14 * RS);
  _Float16* hbuf_lo = (_Float16*)(wsb + 16 * RS);
  _Float16* whi = (_Float16*)(wsb + 18 * RS);
  _Float16* wlo = whi + WTOT;
  float* rotW2 = (float*)(wlo + WTOT);                // [512*256] f32
  int* buckets = (int*)(rotW2 + 512 * 256);
  int* stbuf   = buckets + B_ * H_ * S_;
  // total: 18RS (151.0MB) + 12.06MB + 1.6MB ~= 164.7MB (r8/r12-proven)

  const int Mh = M_ / 2;                     // 1024

  embed_kernel<<<rows, 128, 0, stream>>>(tokens, emb, x);

  for (int l = 0; l < L_; l++) {
    transp_all<<<2816, 256, 0, stream>>>(Wq + (size_t)l * D_ * D_, Wv + (size_t)l * D_ * D_,
                                         Wo + (size_t)l * D_ * D_, W1 + (size_t)l * D_ * M_,
                                         W2 + (size_t)l * M_ * D_, whi, wlo);
    rotw_kernel<<<(D_ * 256) / 256, 256, 0, stream>>>(Wq + (size_t)l * D_ * D_,
                                                      rot + (size_t)l * H_ * DH_ * 32, rotW2);
    transp_cvt<<<dim3(256 / 32, D_ / 32), 256, 0, stream>>>(rotW2, whi + OR_, wlo + OR_, D_, 256);

    ln_h<<<rows / 4, 256, 0, stream>>>(x, hbuf_hi, hbuf_lo, ln1_s + (size_t)l * D_, ln1_b + (size_t)l * D_);

    // fused Q+V+hash projection: B = [WqT ; WvT ; rotW2T] (1280 rows, pitch 512)
    dim3 gqv(1280 / 128, rows / 128);
    gemm_h<0, 0, 0, 1><<<gqv, 256, 0, stream>>>(hbuf_hi, hbuf_lo, whi + OQ_, wlo + OQ_, nullptr,
                                                nullptr, qvr_hi, qvr_lo, rows, 1280, D_, D_, D_);

    argmax_kernel<<<(B_ * H_ * S_) / 256, 256, 0, stream>>>(qvr_hi, qvr_lo, buckets);
    sort_kernel<<<B_ * H_, 64, 0, stream>>>(buckets, stbuf);
    attn_mfma<<<B_ * H_ * NC_, 256, 0, stream>>>(qvr_hi, qvr_lo, stbuf, obuf_hi, obuf_lo);

    dim3 g1(D_ / 128, rows / 128);
    gemm_h<0, 1, 0, 0><<<g1, 256, 0, stream>>>(obuf_hi, obuf_lo, whi + OO_, wlo + OO_, nullptr,
                                               x, nullptr, nullptr, rows, D_, D_, D_, D_);

    ln_h<<<rows / 4, 256, 0, stream>>>(x, hbuf_hi, hbuf_lo, ln2_s + (size_t)l * D_, ln2_b + (size_t)l * D_);

    // FFN in two 1024-column halves (mid planes sized [rows][1024])
    for (int ch = 0; ch < 2; ch++) {
      dim3 gf1(Mh / 128, rows / 128);
      gemm_h<1, 0, 1, 1><<<gf1, 256, 0, stream>>>(hbuf_hi, hbuf_lo,
                                                  whi + O1_ + (size_t)ch * Mh * D_,
                                                  wlo + O1_ + (size_t)ch * Mh * D_,
                                                  b1 + (size_t)l * M_ + ch * Mh,
                                                  nullptr, mid_hi, mid_lo, rows, Mh, D_, D_, D_);
      dim3 gf2(D_ / 128, rows / 128);
      if (ch == 0) {
        gemm_h<0, 1, 0, 0><<<gf2, 256, 0, stream>>>(mid_hi, mid_lo,
                                                    whi + O2_,
                                                    wlo + O2_,
                                                    nullptr, x, nullptr, nullptr,
                                                    rows, D_, Mh, Mh, M_);
      } else {
        gemm_h<1, 1, 0, 0><<<gf2, 256, 0, stream>>>(mid_hi, mid_lo,
                                                    whi + O2_ + (size_t)ch * Mh,
                                                    wlo + O2_ + (size_t)ch * Mh,
                                                    b2 + (size_t)l * D_, x, nullptr, nullptr,
                                                    rows, D_, Mh, Mh, M_);
      }
    }
  }

  ln_f<<<rows / 4, 256, 0, stream>>>(x, x, lnf_s, lnf_b);
}